// Round 1
// baseline (333.685 us; speedup 1.0000x reference)
//
#include <hip/hip_runtime.h>
#include <math.h>

#define BB 4
#define NN 19
#define CC 57
#define HH 512
#define WW 512
#define HWPIX (HH * WW)
#define RADIUS2 1600.0f
#define ROWS_PER_BLOCK 8

// ws layout: 76 * 4 floats: [bce_sum, cnt, l1x_sum, l1y_sum] per (b,n)
__global__ void zero_ws(float* ws) {
    int t = threadIdx.x;
    if (t < BB * NN * 4) ws[t] = 0.0f;
}

__global__ __launch_bounds__(256) void hm_loss_main(
    const float* __restrict__ fm, const float* __restrict__ lm,
    float* __restrict__ ws)
{
    const int bn = blockIdx.y;            // 0..75
    const int b  = bn / NN;
    const int n  = bn % NN;
    const int row0 = blockIdx.x * ROWS_PER_BLOCK;

    const float lx = lm[(b * NN + n) * 2 + 0];
    const float ly = lm[(b * NN + n) * 2 + 1];
    const int x = (int)(lx * (float)HH);   // trunc, matches astype(int32) for non-neg
    const int y = (int)(ly * (float)WW);

    const float* __restrict__ logit = fm + (size_t)(b * CC + n)          * HWPIX;
    const float* __restrict__ predx = fm + (size_t)(b * CC + NN + n)     * HWPIX;
    const float* __restrict__ predy = fm + (size_t)(b * CC + 2 * NN + n) * HWPIX;

    float s_bce = 0.0f, s_cnt = 0.0f, s_l1x = 0.0f, s_l1y = 0.0f;

    const int iters = ROWS_PER_BLOCK * WW / 256;   // 16
    #pragma unroll
    for (int it = 0; it < iters; ++it) {
        int idx = it * 256 + threadIdx.x;          // 0..4095 within chunk
        int i = row0 + (idx >> 9);                 // row
        int j = idx & (WW - 1);                    // col
        int off = i * WW + j;

        float l = logit[off];
        float di = (float)(i - x);
        float dj = (float)(j - y);
        float d2 = di * di + dj * dj;
        bool in = (d2 <= RADIUS2);
        float h = in ? 1.0f : 0.0f;

        // bce = max(l,0) - l*h + log1p(exp(-|l|))
        s_bce += fmaxf(l, 0.0f) - l * h + log1pf(expf(-fabsf(l)));

        if (in) {
            s_cnt += 1.0f;
            float px = predx[off];
            float py = predy[off];
            // |pred_x - (-di/40)| = |pred_x + di/40|
            s_l1x += fabsf(px + di * (1.0f / 40.0f));
            s_l1y += fabsf(py + dj * (1.0f / 40.0f));
        }
    }

    // wave (64-lane) shuffle reduction
    #pragma unroll
    for (int o = 32; o > 0; o >>= 1) {
        s_bce += __shfl_down(s_bce, o);
        s_cnt += __shfl_down(s_cnt, o);
        s_l1x += __shfl_down(s_l1x, o);
        s_l1y += __shfl_down(s_l1y, o);
    }

    __shared__ float red[4][4];   // [wave][quantity]
    int wave = threadIdx.x >> 6;
    int lane = threadIdx.x & 63;
    if (lane == 0) {
        red[wave][0] = s_bce;
        red[wave][1] = s_cnt;
        red[wave][2] = s_l1x;
        red[wave][3] = s_l1y;
    }
    __syncthreads();
    if (threadIdx.x == 0) {
        float a = red[0][0] + red[1][0] + red[2][0] + red[3][0];
        float c = red[0][1] + red[1][1] + red[2][1] + red[3][1];
        float px = red[0][2] + red[1][2] + red[2][2] + red[3][2];
        float py = red[0][3] + red[1][3] + red[2][3] + red[3][3];
        atomicAdd(&ws[bn * 4 + 0], a);
        atomicAdd(&ws[bn * 4 + 1], c);
        atomicAdd(&ws[bn * 4 + 2], px);
        atomicAdd(&ws[bn * 4 + 3], py);
    }
}

__global__ __launch_bounds__(128) void hm_loss_final(
    const float* __restrict__ ws, float* __restrict__ out)
{
    int t = threadIdx.x;
    float term = 0.0f;
    if (t < BB * NN) {
        float bce = ws[t * 4 + 0] * (1.0f / (float)HWPIX);
        float cnt = ws[t * 4 + 1];
        float l1x = ws[t * 4 + 2] / cnt;
        float l1y = ws[t * 4 + 3] / cnt;
        term = 2.0f * bce + l1x + l1y;
    }
    #pragma unroll
    for (int o = 32; o > 0; o >>= 1) term += __shfl_down(term, o);

    __shared__ float red[2];
    if ((t & 63) == 0) red[t >> 6] = term;
    __syncthreads();
    if (t == 0) out[0] = (red[0] + red[1]) * (1.0f / (float)(BB * NN));
}

extern "C" void kernel_launch(void* const* d_in, const int* in_sizes, int n_in,
                              void* d_out, int out_size, void* d_ws, size_t ws_size,
                              hipStream_t stream) {
    const float* fm = (const float*)d_in[0];
    const float* lm = (const float*)d_in[1];
    float* ws  = (float*)d_ws;
    float* out = (float*)d_out;

    zero_ws<<<1, 512, 0, stream>>>(ws);
    dim3 grid(HH / ROWS_PER_BLOCK, BB * NN);   // 64 x 76 = 4864 blocks
    hm_loss_main<<<grid, 256, 0, stream>>>(fm, lm, ws);
    hm_loss_final<<<1, 128, 0, stream>>>(ws, out);
}

// Round 2
// 293.858 us; speedup vs baseline: 1.1355x; 1.1355x over previous
//
#include <hip/hip_runtime.h>
#include <math.h>

#define BB 4
#define NN 19
#define CC 57
#define HH 512
#define WW 512
#define HWPIX (HH * WW)
#define RADIUS2 1600.0f
#define ROWS_PER_BLOCK 8
#define CHUNKS (HH / ROWS_PER_BLOCK)   // 64
#define VEC_PER_ROW (WW / 4)           // 128

// part layout: [bn (76)][chunk (64)] of float4 {bce_sum, cnt, l1x_sum, l1y_sum}
// Every slot is written unconditionally by its block -> no zero-init needed.

__global__ __launch_bounds__(256) void hm_main(
    const float* __restrict__ fm, const float* __restrict__ lm,
    float4* __restrict__ part)
{
    const int bn = blockIdx.y;            // 0..75
    const int b  = bn / NN;
    const int n  = bn % NN;
    const int chunk = blockIdx.x;         // 0..63
    const int row0  = chunk * ROWS_PER_BLOCK;

    const float lx = lm[bn * 2 + 0];
    const float ly = lm[bn * 2 + 1];
    const int x = (int)(lx * 512.0f);     // trunc == astype(int32) for non-neg
    const int y = (int)(ly * 512.0f);

    const float4* __restrict__ logit =
        (const float4*)(fm + (size_t)(b * CC + n) * HWPIX) + row0 * VEC_PER_ROW;
    const float4* __restrict__ predx =
        (const float4*)(fm + (size_t)(b * CC + NN + n) * HWPIX) + row0 * VEC_PER_ROW;
    const float4* __restrict__ predy =
        (const float4*)(fm + (size_t)(b * CC + 2 * NN + n) * HWPIX) + row0 * VEC_PER_ROW;

    float s_bce = 0.0f, s_cnt = 0.0f, s_l1x = 0.0f, s_l1y = 0.0f;

    #pragma unroll
    for (int it = 0; it < 4; ++it) {
        int v  = it * 256 + threadIdx.x;   // 0..1023 vec4 index within chunk
        int r  = v >> 7;                   // row within chunk (128 vec4 per row)
        int c4 = v & (VEC_PER_ROW - 1);
        int i  = row0 + r;
        float di = (float)(i - x);
        float di2 = di * di;

        float4 l4 = logit[v];
        float lv[4] = { l4.x, l4.y, l4.z, l4.w };

        float djv[4];
        bool  inm[4];
        bool  any = false;
        #pragma unroll
        for (int e = 0; e < 4; ++e) {
            float dj = (float)(c4 * 4 + e - y);
            djv[e] = dj;
            float d2 = fmaf(dj, dj, di2);
            inm[e] = (d2 <= RADIUS2);      // sqrt(d2)<=40 <=> d2<=1600 exactly
            any |= inm[e];
        }

        #pragma unroll
        for (int e = 0; e < 4; ++e) {
            float l = lv[e];
            float a = fabsf(l);
            // softplus(-a) = log1p(exp(-a)); fast native version, abs err ~1e-7
            float sp = __logf(1.0f + __expf(-a));
            s_bce += fmaxf(l, 0.0f) - (inm[e] ? l : 0.0f) + sp;
        }

        if (any) {
            float4 px4 = predx[v];
            float4 py4 = predy[v];
            float pxv[4] = { px4.x, px4.y, px4.z, px4.w };
            float pyv[4] = { py4.x, py4.y, py4.z, py4.w };
            #pragma unroll
            for (int e = 0; e < 4; ++e) {
                if (inm[e]) {
                    s_cnt += 1.0f;
                    // |pred - (-d/40)| = |pred + d*0.025|
                    s_l1x += fabsf(fmaf(di,     0.025f, pxv[e]));
                    s_l1y += fabsf(fmaf(djv[e], 0.025f, pyv[e]));
                }
            }
        }
    }

    // 64-lane wave shuffle reduction
    #pragma unroll
    for (int o = 32; o > 0; o >>= 1) {
        s_bce += __shfl_down(s_bce, o);
        s_cnt += __shfl_down(s_cnt, o);
        s_l1x += __shfl_down(s_l1x, o);
        s_l1y += __shfl_down(s_l1y, o);
    }

    __shared__ float red[4][4];
    int wave = threadIdx.x >> 6;
    int lane = threadIdx.x & 63;
    if (lane == 0) {
        red[wave][0] = s_bce;
        red[wave][1] = s_cnt;
        red[wave][2] = s_l1x;
        red[wave][3] = s_l1y;
    }
    __syncthreads();
    if (threadIdx.x == 0) {
        float4 p;
        p.x = red[0][0] + red[1][0] + red[2][0] + red[3][0];
        p.y = red[0][1] + red[1][1] + red[2][1] + red[3][1];
        p.z = red[0][2] + red[1][2] + red[2][2] + red[3][2];
        p.w = red[0][3] + red[1][3] + red[2][3] + red[3][3];
        part[bn * CHUNKS + chunk] = p;
    }
}

__global__ __launch_bounds__(256) void hm_final(
    const float4* __restrict__ part, float* __restrict__ out)
{
    int t = threadIdx.x;
    int wave = t >> 6;          // 0..3
    int lane = t & 63;
    float acc = 0.0f;

    #pragma unroll
    for (int k = 0; k < 19; ++k) {
        int bn = wave * 19 + k;                 // 4 waves x 19 = 76
        float4 p = part[bn * CHUNKS + lane];    // lane <-> chunk, coalesced
        float pb = p.x, pc = p.y, p1 = p.z, p2 = p.w;
        #pragma unroll
        for (int o = 32; o > 0; o >>= 1) {
            pb += __shfl_down(pb, o);
            pc += __shfl_down(pc, o);
            p1 += __shfl_down(p1, o);
            p2 += __shfl_down(p2, o);
        }
        if (lane == 0)
            acc += 2.0f * (pb * (1.0f / (float)HWPIX)) + p1 / pc + p2 / pc;
    }

    __shared__ float red[4];
    if (lane == 0) red[wave] = acc;
    __syncthreads();
    if (t == 0) out[0] = (red[0] + red[1] + red[2] + red[3]) * (1.0f / (float)(BB * NN));
}

extern "C" void kernel_launch(void* const* d_in, const int* in_sizes, int n_in,
                              void* d_out, int out_size, void* d_ws, size_t ws_size,
                              hipStream_t stream) {
    const float* fm = (const float*)d_in[0];
    const float* lm = (const float*)d_in[1];
    float4* part = (float4*)d_ws;
    float* out = (float*)d_out;

    dim3 grid(CHUNKS, BB * NN);   // 64 x 76 = 4864 blocks
    hm_main<<<grid, 256, 0, stream>>>(fm, lm, part);
    hm_final<<<1, 256, 0, stream>>>(part, out);
}